// Round 10
// baseline (139.933 us; speedup 1.0000x reference)
//
#include <hip/hip_runtime.h>
#include <hip/hip_bf16.h>

#define BS   8
#define NREL 16
#define NN   512
#define EMB  256

typedef float f32x4 __attribute__((ext_vector_type(4)));
typedef short s16x8 __attribute__((ext_vector_type(8)));

// f32 -> bf16 bits, round-to-nearest-even (cold kernels)
__device__ __forceinline__ unsigned short f2bf_bits(float f) {
    union { float f; unsigned u; } v; v.f = f;
    unsigned r = (v.u + 0x7FFFu + ((v.u >> 16) & 1u)) >> 16;
    return (unsigned short)r;
}

// hw cvt path (compiler emits v_cvt_pk_bf16_f32 when paired)
__device__ __forceinline__ unsigned short f2bf_hw(float f) {
    union { __hip_bfloat16 h; unsigned short u; } v;
    v.h = __float2bfloat16(f);
    return v.u;
}

// ---------------------------------------------------------------------------
// K0: transpose W_r[16][256][256] + W_0[256][256] -> wT[17][h][d] bf16
// ---------------------------------------------------------------------------
__global__ __launch_bounds__(256) void k0_transpose(
        const float* __restrict__ Wr, const float* __restrict__ W0,
        unsigned short* __restrict__ wT) {
    __shared__ float tile[32][33];
    int bid = blockIdx.x;
    int rel = bid / 64;          // 0..16
    int t   = bid % 64;
    int d0  = (t & 7) * 32;
    int h0  = (t >> 3) * 32;
    int tx  = threadIdx.x & 31;
    int ty  = threadIdx.x >> 5;  // 0..7
    const float* src = (rel < NREL) ? (Wr + rel * (EMB * EMB)) : W0;
#pragma unroll
    for (int k = 0; k < 4; ++k) {
        int d = d0 + ty + k * 8;
        tile[ty + k * 8][tx] = src[d * EMB + h0 + tx];
    }
    __syncthreads();
#pragma unroll
    for (int k = 0; k < 4; ++k) {
        int h = h0 + ty + k * 8;
        wT[(rel * EMB + h) * EMB + d0 + tx] = f2bf_bits(tile[tx][ty + k * 8]);
    }
}

// ---------------------------------------------------------------------------
// K0b: convert F[8][512][256] f32 -> Fbf bf16 row-major
// ---------------------------------------------------------------------------
__global__ __launch_bounds__(256) void k0b_convF(
        const float* __restrict__ F, unsigned short* __restrict__ Fbf) {
    long i = ((long)blockIdx.x * 256 + threadIdx.x) * 8;
    f32x4 x0 = *(const f32x4*)(F + i);
    f32x4 x1 = *(const f32x4*)(F + i + 4);
    s16x8 v;
    v[0] = (short)f2bf_bits(x0[0]); v[1] = (short)f2bf_bits(x0[1]);
    v[2] = (short)f2bf_bits(x0[2]); v[3] = (short)f2bf_bits(x0[3]);
    v[4] = (short)f2bf_bits(x1[0]); v[5] = (short)f2bf_bits(x1[1]);
    v[6] = (short)f2bf_bits(x1[2]); v[7] = (short)f2bf_bits(x1[3]);
    *(s16x8*)(Fbf + i) = v;
}

// ---------------------------------------------------------------------------
// K1: FW[b][rel][m][h] = sum_d F[b][m][d] * W[rel][d][h]
//   D[h][m] = wT(A) x Fbf(B), MFMA 16x16x32 bf16, all-bf16 operand loads.
//   rel<16  -> FW fragment-major: [(b*16+rel)*64 + m/8][h][m%8] bf16
//   rel==16 -> F2f f32 row-major [b][n][h]
// ---------------------------------------------------------------------------
__global__ __launch_bounds__(256) void k1_fw(
        const unsigned short* __restrict__ Fbf, const unsigned short* __restrict__ wT,
        unsigned short* __restrict__ FW, float* __restrict__ F2f) {
    int bid = blockIdx.x;
    int b   = bid & 7;
    int q   = bid >> 3;          // 0..135
    int rel = q % 17;
    int mt  = q / 17;            // 0..7
    int tid = threadIdx.x;
    int w   = tid >> 6;          // 0..3
    int l   = tid & 63;
    int lg  = l >> 4;            // 0..3
    int lr  = l & 15;

    int h0 = w * 64;             // wave's 64 h-rows (M-dim)
    int m0 = mt * 64;            // block's 64 m-cols (N-dim)

    const unsigned short* wt = wT + rel * (EMB * EMB);
    const unsigned short* Fb = Fbf + (long)b * (NN * EMB);

    f32x4 acc[4][4];
#pragma unroll
    for (int i = 0; i < 4; ++i)
#pragma unroll
        for (int j = 0; j < 4; ++j) acc[i][j] = (f32x4){0.f, 0.f, 0.f, 0.f};

#pragma unroll 2
    for (int kk = 0; kk < EMB; kk += 32) {
        s16x8 afrag[4];
#pragma unroll
        for (int hi = 0; hi < 4; ++hi) {
            int row = h0 + hi * 16 + lr;
            afrag[hi] = *(const s16x8*)(wt + row * EMB + kk + lg * 8);
        }
        s16x8 bfrag[4];
#pragma unroll
        for (int bi = 0; bi < 4; ++bi) {
            int m = m0 + bi * 16 + lr;
            bfrag[bi] = *(const s16x8*)(Fb + m * EMB + kk + lg * 8);
        }
#pragma unroll
        for (int hi = 0; hi < 4; ++hi)
#pragma unroll
            for (int bi = 0; bi < 4; ++bi)
                acc[hi][bi] = __builtin_amdgcn_mfma_f32_16x16x32_bf16(
                    afrag[hi], bfrag[bi], acc[hi][bi], 0, 0, 0);
    }

    // Epilogue: D rows = h, cols = m.  C layout: col = lane&15, row = (lane>>4)*4+j
#pragma unroll
    for (int hi = 0; hi < 4; ++hi) {
#pragma unroll
        for (int bi = 0; bi < 4; ++bi) {
            int m  = m0 + bi * 16 + lr;
            int kg = m >> 3, ko = m & 7;
#pragma unroll
            for (int j = 0; j < 4; ++j) {
                int h = h0 + hi * 16 + lg * 4 + j;
                if (rel < NREL)
                    FW[(long)((b * 16 + rel) * 64 + kg) * 2048 + h * 8 + ko] =
                        f2bf_bits(acc[hi][bi][j]);
                else
                    F2f[((long)b * NN + m) * EMB + h] = acc[hi][bi][j];
            }
        }
    }
}

// ---------------------------------------------------------------------------
// K2: part[rg][b][n][h] = sum_{r in rg(2 rels)} sum_m adj[b][r][n][m]*FW[b][r][m][h]
//   grid 512 = 8b (XCD-grouped) x 8nt(64 rows) x 8rg(2 rels)
//   block 256 thr = 4 waves (2 wr x 2 wc-parity).  Wave: 32 rows x 256 cols,
//   slices 2i+wc, acc[2][16].  No LDS/barriers in loop.
//   Adjacency: NON-TEMPORAL loads (single-use; keep FW resident in L2),
//   distance-1 register prefetch issued first.  B-frags from fragment-major
//   FW (L2-resident now) into bfr[16].  part stores non-temporal.
//   s_setprio(1) around the MFMA cluster (T5).
// ---------------------------------------------------------------------------
__global__ __launch_bounds__(256, 2) void k2_main(
        const float* __restrict__ adj, const unsigned short* __restrict__ FW,
        float* __restrict__ part) {
    __shared__ float lf[16384];        // 64KB, epilogue only
    int bid = blockIdx.x;
    int b   = bid & 7;
    int t   = bid >> 3;          // 0..63
    int nt  = t & 7;
    int rg  = t >> 3;            // 0..7
    int tid = threadIdx.x;
    int w   = tid >> 6;          // 0..3
    int l   = tid & 63;
    int lg  = l >> 4, lr = l & 15;
    int wr  = w >> 1;            // 0..1 : 32-row group
    int wc  = w & 1;             // 0..1 : K-slice parity

    int nrow = nt * 64 + wr * 32;     // wave's 32 output rows

    f32x4 acc0[16], acc1[16];
#pragma unroll
    for (int i = 0; i < 16; ++i) {
        acc0[i] = (f32x4){0.f, 0.f, 0.f, 0.f};
        acc1[i] = (f32x4){0.f, 0.f, 0.f, 0.f};
    }

    // adjacency: rows nrow+lr and nrow+16+lr, 32-float chunk at lg*8
    const float* adjb0 =
        adj + (((long)(b * 16 + rg * 2)) * NN + nrow + lr) * NN + lg * 8;
    const float* adjb1 = adjb0 + 16 * NN;
    // per-lane B-frag base: frag f of slice sl at
    //   fwb + (sl>>4)*131072 + ((sl&15)*4 + lg)*2048 + lr*8 + f*128
    const unsigned short* fwb =
        FW + (long)(b * 16 + rg * 2) * 131072 + lg * 2048 + lr * 8;

    f32x4 ax[2][2], ay[2][2];          // [slot][row group]

    // ---- prologue: adjacency slice wc -> slot 0 (non-temporal)
    {
        const float* p0 = adjb0 + wc * 32;
        const float* p1 = adjb1 + wc * 32;
        ax[0][0] = __builtin_nontemporal_load((const f32x4*)p0);
        ay[0][0] = __builtin_nontemporal_load((const f32x4*)(p0 + 4));
        ax[0][1] = __builtin_nontemporal_load((const f32x4*)p1);
        ay[0][1] = __builtin_nontemporal_load((const f32x4*)(p1 + 4));
    }

#pragma unroll
    for (int i = 0; i < 16; ++i) {
        // 1. adjacency prefetch for slice 2(i+1)+wc (non-temporal, issued first)
        if (i + 1 < 16) {
            int sn = 2 * (i + 1) + wc;
            long ao = (long)(sn >> 4) * (NN * NN) + (sn & 15) * 32;
            const float* p0 = adjb0 + ao;
            const float* p1 = adjb1 + ao;
            if (((i + 1) & 1) == 0) {
                ax[0][0] = __builtin_nontemporal_load((const f32x4*)p0);
                ay[0][0] = __builtin_nontemporal_load((const f32x4*)(p0 + 4));
                ax[0][1] = __builtin_nontemporal_load((const f32x4*)p1);
                ay[0][1] = __builtin_nontemporal_load((const f32x4*)(p1 + 4));
            } else {
                ax[1][0] = __builtin_nontemporal_load((const f32x4*)p0);
                ay[1][0] = __builtin_nontemporal_load((const f32x4*)(p0 + 4));
                ax[1][1] = __builtin_nontemporal_load((const f32x4*)p1);
                ay[1][1] = __builtin_nontemporal_load((const f32x4*)(p1 + 4));
            }
        }

        // 2. B-frag loads for this slice (L2-resident FW; 16 independent dwordx4)
        int sl = 2 * i + wc;
        const unsigned short* pk =
            fwb + (long)(sl >> 4) * 131072 + ((sl & 15) * 4) * 2048;
        s16x8 bfr[16];
#pragma unroll
        for (int f = 0; f < 16; ++f)
            bfr[f] = *(const s16x8*)(pk + f * 128);

        // 3. convert adjacency slice -> 2 A-frags (hw v_cvt_pk path)
        f32x4 x00 = ax[i & 1][0], x01 = ay[i & 1][0];
        f32x4 x10 = ax[i & 1][1], x11 = ay[i & 1][1];
        s16x8 a0, a1;
        a0[0] = (short)f2bf_hw(x00[0]); a0[1] = (short)f2bf_hw(x00[1]);
        a0[2] = (short)f2bf_hw(x00[2]); a0[3] = (short)f2bf_hw(x00[3]);
        a0[4] = (short)f2bf_hw(x01[0]); a0[5] = (short)f2bf_hw(x01[1]);
        a0[6] = (short)f2bf_hw(x01[2]); a0[7] = (short)f2bf_hw(x01[3]);
        a1[0] = (short)f2bf_hw(x10[0]); a1[1] = (short)f2bf_hw(x10[1]);
        a1[2] = (short)f2bf_hw(x10[2]); a1[3] = (short)f2bf_hw(x10[3]);
        a1[4] = (short)f2bf_hw(x11[0]); a1[5] = (short)f2bf_hw(x11[1]);
        a1[6] = (short)f2bf_hw(x11[2]); a1[7] = (short)f2bf_hw(x11[3]);

        // 4. MFMA cluster (priority-boosted)
        __builtin_amdgcn_s_setprio(1);
#pragma unroll
        for (int f = 0; f < 16; ++f) {
            acc0[f] = __builtin_amdgcn_mfma_f32_16x16x32_bf16(a0, bfr[f], acc0[f], 0, 0, 0);
            acc1[f] = __builtin_amdgcn_mfma_f32_16x16x32_bf16(a1, bfr[f], acc1[f], 0, 0, 0);
        }
        __builtin_amdgcn_s_setprio(0);
    }

    // ---- cross-wc reduce via LDS (stride-64 floats: 2 lanes/bank, free)
    __syncthreads();
    if (wc == 1) {
#pragma unroll
        for (int g = 0; g < 2; ++g)
#pragma unroll
            for (int f = 0; f < 16; ++f)
#pragma unroll
                for (int j = 0; j < 4; ++j)
                    lf[wr * 8192 + ((g * 16 + f) * 4 + j) * 64 + l] =
                        g ? acc1[f][j] : acc0[f][j];
    }
    __syncthreads();
    if (wc == 0) {
        float* pp = part + ((long)rg * BS + b) * (NN * EMB);
#pragma unroll
        for (int g = 0; g < 2; ++g)
#pragma unroll
            for (int f = 0; f < 16; ++f) {
                int h = f * 16 + lr;
#pragma unroll
                for (int j = 0; j < 4; ++j) {
                    int n = nrow + g * 16 + lg * 4 + j;
                    float v = (g ? acc1[f][j] : acc0[f][j]) +
                              lf[wr * 8192 + ((g * 16 + f) * 4 + j) * 64 + l];
                    __builtin_nontemporal_store(v, &pp[(long)n * EMB + h]);
                }
            }
    }
}

// ---------------------------------------------------------------------------
// K3: out = relu(sum over 8 rg slices + F2f), vectorized f32x4
// ---------------------------------------------------------------------------
__global__ __launch_bounds__(256) void k3_reduce(
        const float* __restrict__ part, const float* __restrict__ F2f,
        float* __restrict__ out) {
    const long PS = (long)BS * NN * EMB;   // 1,048,576 floats per rg slice
    long i = ((long)blockIdx.x * 256 + threadIdx.x) * 4;
    f32x4 s = __builtin_nontemporal_load((const f32x4*)(part + i));
#pragma unroll
    for (int rg = 1; rg < 8; ++rg)
        s += __builtin_nontemporal_load((const f32x4*)(part + i + (long)rg * PS));
    s += *(const f32x4*)(F2f + i);
    f32x4 r;
#pragma unroll
    for (int j = 0; j < 4; ++j) r[j] = s[j] > 0.f ? s[j] : 0.f;
    __builtin_nontemporal_store(r, (f32x4*)(out + i));
}

// ---------------------------------------------------------------------------
extern "C" void kernel_launch(void* const* d_in, const int* in_sizes, int n_in,
                              void* d_out, int out_size, void* d_ws, size_t ws_size,
                              hipStream_t stream) {
    const float* F   = (const float*)d_in[0];   // [8][512][256]
    const float* adj = (const float*)d_in[1];   // [8][16][512][512]
    const float* Wr  = (const float*)d_in[2];   // [16][256][256]
    const float* W0  = (const float*)d_in[3];   // [256][256]
    float* out = (float*)d_out;                 // [8][512][256]

    unsigned short* wT  = (unsigned short*)d_ws;             // 17*256*256 bf16
    unsigned short* Fbf = wT + 17 * 256 * 256;               // 8*512*256 bf16
    unsigned short* FW  = Fbf + (long)8 * 512 * 256;         // 8*16*64*2048 bf16
    float* F2f  = (float*)(FW + (long)8 * 16 * 64 * 2048);   // 8*512*256 f32
    float* part = F2f + (long)8 * 512 * 256;                 // 8*8*512*256 f32

    k0_transpose<<<17 * 64, 256, 0, stream>>>(Wr, W0, wT);
    k0b_convF<<<512, 256, 0, stream>>>(F, Fbf);
    k1_fw<<<1088, 256, 0, stream>>>(Fbf, wT, FW, F2f);
    k2_main<<<512, 256, 0, stream>>>(adj, FW, part);
    k3_reduce<<<1024, 256, 0, stream>>>(part, F2f, out);
}

// Round 11
// 99.090 us; speedup vs baseline: 1.4122x; 1.4122x over previous
//
#include <hip/hip_runtime.h>
#include <hip/hip_bf16.h>

#define BS   8
#define NREL 16
#define NN   512
#define EMB  256

typedef float f32x4 __attribute__((ext_vector_type(4)));
typedef short s16x8 __attribute__((ext_vector_type(8)));

// f32 -> bf16 bits, round-to-nearest-even (cold paths)
__device__ __forceinline__ unsigned short f2bf_bits(float f) {
    union { float f; unsigned u; } v; v.f = f;
    unsigned r = (v.u + 0x7FFFu + ((v.u >> 16) & 1u)) >> 16;
    return (unsigned short)r;
}

// hw cvt path (compiler emits v_cvt_pk_bf16_f32 when paired)
__device__ __forceinline__ unsigned short f2bf_hw(float f) {
    union { __hip_bfloat16 h; unsigned short u; } v;
    v.h = __float2bfloat16(f);
    return v.u;
}

// ---------------------------------------------------------------------------
// K0: fused prep.  bid < 1088: transpose W_r + W_0 -> wT[17][h][d] bf16.
//     bid >= 1088: convert F f32 -> Fbf bf16 (512 blocks x 2048 elems).
// ---------------------------------------------------------------------------
__global__ __launch_bounds__(256) void k0_prep(
        const float* __restrict__ Wr, const float* __restrict__ W0,
        const float* __restrict__ F,
        unsigned short* __restrict__ wT, unsigned short* __restrict__ Fbf) {
    int bid = blockIdx.x;
    if (bid < 1088) {
        __shared__ float tile[32][33];
        int rel = bid / 64;          // 0..16
        int t   = bid % 64;
        int d0  = (t & 7) * 32;
        int h0  = (t >> 3) * 32;
        int tx  = threadIdx.x & 31;
        int ty  = threadIdx.x >> 5;  // 0..7
        const float* src = (rel < NREL) ? (Wr + rel * (EMB * EMB)) : W0;
#pragma unroll
        for (int k = 0; k < 4; ++k) {
            int d = d0 + ty + k * 8;
            tile[ty + k * 8][tx] = src[d * EMB + h0 + tx];
        }
        __syncthreads();
#pragma unroll
        for (int k = 0; k < 4; ++k) {
            int h = h0 + ty + k * 8;
            wT[(rel * EMB + h) * EMB + d0 + tx] = f2bf_bits(tile[tx][ty + k * 8]);
        }
    } else {
        long i = ((long)(bid - 1088) * 256 + threadIdx.x) * 8;
        f32x4 x0 = *(const f32x4*)(F + i);
        f32x4 x1 = *(const f32x4*)(F + i + 4);
        s16x8 v;
        v[0] = (short)f2bf_bits(x0[0]); v[1] = (short)f2bf_bits(x0[1]);
        v[2] = (short)f2bf_bits(x0[2]); v[3] = (short)f2bf_bits(x0[3]);
        v[4] = (short)f2bf_bits(x1[0]); v[5] = (short)f2bf_bits(x1[1]);
        v[6] = (short)f2bf_bits(x1[2]); v[7] = (short)f2bf_bits(x1[3]);
        *(s16x8*)(Fbf + i) = v;
    }
}

// ---------------------------------------------------------------------------
// K1: FW[b][rel][m][h] = sum_d F[b][m][d] * W[rel][d][h]
//   D[h][m] = wT(A) x Fbf(B), MFMA 16x16x32 bf16; distance-1 fragment dbuf.
//   rel<16  -> FW fragment-major: [(b*16+rel)*64 + m/8][h][m%8] bf16
//   rel==16 -> F2f f32 row-major [b][n][h]
// ---------------------------------------------------------------------------
__global__ __launch_bounds__(256) void k1_fw(
        const unsigned short* __restrict__ Fbf, const unsigned short* __restrict__ wT,
        unsigned short* __restrict__ FW, float* __restrict__ F2f) {
    int bid = blockIdx.x;
    int b   = bid & 7;
    int q   = bid >> 3;          // 0..135
    int rel = q % 17;
    int mt  = q / 17;            // 0..7
    int tid = threadIdx.x;
    int w   = tid >> 6;          // 0..3
    int l   = tid & 63;
    int lg  = l >> 4;            // 0..3
    int lr  = l & 15;

    int h0 = w * 64;             // wave's 64 h-rows (M-dim)
    int m0 = mt * 64;            // block's 64 m-cols (N-dim)

    const unsigned short* wt = wT + rel * (EMB * EMB) + lg * 8;
    const unsigned short* Fb = Fbf + (long)b * (NN * EMB) + lg * 8;

    f32x4 acc[4][4];
#pragma unroll
    for (int i = 0; i < 4; ++i)
#pragma unroll
        for (int j = 0; j < 4; ++j) acc[i][j] = (f32x4){0.f, 0.f, 0.f, 0.f};

    s16x8 afr[2][4], bfr[2][4];
    // preload kk=0
#pragma unroll
    for (int hi = 0; hi < 4; ++hi)
        afr[0][hi] = *(const s16x8*)(wt + (h0 + hi * 16 + lr) * EMB);
#pragma unroll
    for (int bi = 0; bi < 4; ++bi)
        bfr[0][bi] = *(const s16x8*)(Fb + (m0 + bi * 16 + lr) * EMB);

#pragma unroll
    for (int kk = 0; kk < 8; ++kk) {
        int cur = kk & 1, nxt = cur ^ 1;
        if (kk < 7) {
            int ko = (kk + 1) * 32;
#pragma unroll
            for (int hi = 0; hi < 4; ++hi)
                afr[nxt][hi] = *(const s16x8*)(wt + (h0 + hi * 16 + lr) * EMB + ko);
#pragma unroll
            for (int bi = 0; bi < 4; ++bi)
                bfr[nxt][bi] = *(const s16x8*)(Fb + (m0 + bi * 16 + lr) * EMB + ko);
        }
#pragma unroll
        for (int hi = 0; hi < 4; ++hi)
#pragma unroll
            for (int bi = 0; bi < 4; ++bi)
                acc[hi][bi] = __builtin_amdgcn_mfma_f32_16x16x32_bf16(
                    afr[cur][hi], bfr[cur][bi], acc[hi][bi], 0, 0, 0);
    }

    // Epilogue: D rows = h, cols = m.  C layout: col = lane&15, row = (lane>>4)*4+j
#pragma unroll
    for (int hi = 0; hi < 4; ++hi) {
#pragma unroll
        for (int bi = 0; bi < 4; ++bi) {
            int m  = m0 + bi * 16 + lr;
            int kg = m >> 3, ko = m & 7;
#pragma unroll
            for (int j = 0; j < 4; ++j) {
                int h = h0 + hi * 16 + lg * 4 + j;
                if (rel < NREL)
                    FW[(long)((b * 16 + rel) * 64 + kg) * 2048 + h * 8 + ko] =
                        f2bf_bits(acc[hi][bi][j]);
                else
                    F2f[((long)b * NN + m) * EMB + h] = acc[hi][bi][j];
            }
        }
    }
}

// ---------------------------------------------------------------------------
// K2: part[rg][b][n][h] = sum_{r in rg(2 rels)} sum_m adj[b][r][n][m]*FW[b][r][m][h]
//   grid 256 = 8b (XCD-pinned) x 4nt(128 rows) x 8rg(2 rels), 1 block/CU
//   block 512 thr = 8 waves = 4 wr(32-row groups) x 2 wc(K-slice parity).
//   Wave: 32 rows x 256 cols, acc[2][16].  FW re-read cut to 4x (nt=4).
//   Reg-staged T14 pipeline (round-8 primitives): per iter stage one slice-
//   PAIR (32KB, lane-contiguous conflict-free ds_write_b128), double-buffered;
//   adjacency distance-1 reg prefetch; lgkmcnt(0)+sched_barrier+raw s_barrier;
//   no vmcnt(0) in loop.  Epilogue cross-parity reduce in 2 chunks via LDS.
// ---------------------------------------------------------------------------
__global__ __launch_bounds__(512, 2) void k2_main(
        const float* __restrict__ adj, const unsigned short* __restrict__ FW,
        float* __restrict__ part) {
    __shared__ unsigned short Blds[2][16384];   // [buf][pair: 2 slices x 8192 sh] 64KB
    int bid = blockIdx.x;
    int b   = bid & 7;
    int t   = bid >> 3;          // 0..31
    int nt  = t & 3;
    int rg  = t >> 2;            // 0..7
    int tid = threadIdx.x;
    int w   = tid >> 6;          // 0..7
    int l   = tid & 63;
    int lg  = l >> 4, lr = l & 15;
    int wr  = w >> 1;            // 0..3 : 32-row group
    int wc  = w & 1;             // 0..1 : K-slice parity

    int nrow = nt * 128 + wr * 32;    // wave's 32 output rows

    f32x4 acc0[16], acc1[16];
#pragma unroll
    for (int i = 0; i < 16; ++i) {
        acc0[i] = (f32x4){0.f, 0.f, 0.f, 0.f};
        acc1[i] = (f32x4){0.f, 0.f, 0.f, 0.f};
    }

    // adjacency: rows nrow+lr and nrow+16+lr, 32-float chunk at lg*8
    const float* adjb0 =
        adj + (((long)(b * 16 + rg * 2)) * NN + nrow + lr) * NN + lg * 8;
    const float* adjb1 = adjb0 + 16 * NN;
    const unsigned short* fwb = FW + (long)(b * 16 + rg * 2) * 131072;

    // staging: pair p (slices 2p,2p+1) = 16384 contiguous shorts at
    //   rel(p>>3)*131072 + (p&7)*16384.  Thread stages 4 x 16B lane-contiguous.
    s16x8 fwr[4];                      // one pair in flight (64B/thread)
    f32x4 ax[2][2], ay[2][2];          // [slot][row group]

#define POFF(p) ((long)((p) >> 3) * 131072 + ((p) & 7) * 16384)

    // ---- prologue ----
    {   // pair 0: load regs, write buf0
        const unsigned short* s = fwb + POFF(0) + tid * 8;
#pragma unroll
        for (int c = 0; c < 4; ++c) fwr[c] = *(const s16x8*)(s + c * 4096);
#pragma unroll
        for (int c = 0; c < 4; ++c)
            *(s16x8*)(&Blds[0][c * 4096 + tid * 8]) = fwr[c];
    }
    {   // adjacency slice wc -> slot 0 (both row groups)
        const float* p0 = adjb0 + wc * 32;
        const float* p1 = adjb1 + wc * 32;
        ax[0][0] = *(const f32x4*)p0; ay[0][0] = *(const f32x4*)(p0 + 4);
        ax[0][1] = *(const f32x4*)p1; ay[0][1] = *(const f32x4*)(p1 + 4);
    }
    {   // pair 1 regs
        const unsigned short* s = fwb + POFF(1) + tid * 8;
#pragma unroll
        for (int c = 0; c < 4; ++c) fwr[c] = *(const s16x8*)(s + c * 4096);
    }
    asm volatile("s_waitcnt lgkmcnt(0)" ::: "memory");
    __builtin_amdgcn_sched_barrier(0);
    __builtin_amdgcn_s_barrier();
    asm volatile("" ::: "memory");

#pragma unroll
    for (int i = 0; i < 16; ++i) {
        // 1. issue adjacency slice 2(i+1)+wc into the other slot
        if (i + 1 < 16) {
            int sl = 2 * (i + 1) + wc;
            long ao = (long)(sl >> 4) * (NN * NN) + (sl & 15) * 32;
            const float* p0 = adjb0 + ao;
            const float* p1 = adjb1 + ao;
            if (((i + 1) & 1) == 0) {
                ax[0][0] = *(const f32x4*)p0; ay[0][0] = *(const f32x4*)(p0 + 4);
                ax[0][1] = *(const f32x4*)p1; ay[0][1] = *(const f32x4*)(p1 + 4);
            } else {
                ax[1][0] = *(const f32x4*)p0; ay[1][0] = *(const f32x4*)(p0 + 4);
                ax[1][1] = *(const f32x4*)p1; ay[1][1] = *(const f32x4*)(p1 + 4);
            }
        }

        // 2. compute slice 2i+wc from Blds[i&1] (parity half wc)
        f32x4 x00 = ax[i & 1][0], x01 = ay[i & 1][0];
        f32x4 x10 = ax[i & 1][1], x11 = ay[i & 1][1];
        s16x8 a0, a1;
        a0[0] = (short)f2bf_hw(x00[0]); a0[1] = (short)f2bf_hw(x00[1]);
        a0[2] = (short)f2bf_hw(x00[2]); a0[3] = (short)f2bf_hw(x00[3]);
        a0[4] = (short)f2bf_hw(x01[0]); a0[5] = (short)f2bf_hw(x01[1]);
        a0[6] = (short)f2bf_hw(x01[2]); a0[7] = (short)f2bf_hw(x01[3]);
        a1[0] = (short)f2bf_hw(x10[0]); a1[1] = (short)f2bf_hw(x10[1]);
        a1[2] = (short)f2bf_hw(x10[2]); a1[3] = (short)f2bf_hw(x10[3]);
        a1[4] = (short)f2bf_hw(x11[0]); a1[5] = (short)f2bf_hw(x11[1]);
        a1[6] = (short)f2bf_hw(x11[2]); a1[7] = (short)f2bf_hw(x11[3]);

        const unsigned short* bl = &Blds[i & 1][wc * 8192 + lg * 2048];
#pragma unroll
        for (int f = 0; f < 16; ++f) {
            s16x8 bf = *(const s16x8*)(bl + (f * 16 + lr) * 8);
            acc0[f] = __builtin_amdgcn_mfma_f32_16x16x32_bf16(a0, bf, acc0[f], 0, 0, 0);
            acc1[f] = __builtin_amdgcn_mfma_f32_16x16x32_bf16(a1, bf, acc1[f], 0, 0, 0);
        }
        asm volatile("" ::: "memory");   // ds_reads above, ds_writes below

        // 3. ds_write pair i+1; 4. issue pair i+2 regs; barrier
        if (i + 1 < 16) {
            unsigned short* dst = &Blds[(i + 1) & 1][tid * 8];
#pragma unroll
            for (int c = 0; c < 4; ++c) *(s16x8*)(dst + c * 4096) = fwr[c];
            if (i + 2 < 16) {
                const unsigned short* s = fwb + POFF(i + 2) + tid * 8;
#pragma unroll
                for (int c = 0; c < 4; ++c) fwr[c] = *(const s16x8*)(s + c * 4096);
            }
            asm volatile("s_waitcnt lgkmcnt(0)" ::: "memory");
            __builtin_amdgcn_sched_barrier(0);
            __builtin_amdgcn_s_barrier();
            asm volatile("" ::: "memory");
        }
    }
#undef POFF

    // ---- cross-wc reduce via LDS, 2 chunks (g = row-group), 16384 floats each
    float* lf = (float*)Blds;          // 16384 floats = 64KB
    float* pp = part + ((long)rg * BS + b) * (NN * EMB);
#pragma unroll
    for (int g = 0; g < 2; ++g) {
        __syncthreads();
        if (wc == 1) {
#pragma unroll
            for (int f = 0; f < 16; ++f)
#pragma unroll
                for (int j = 0; j < 4; ++j)
                    lf[wr * 4096 + (f * 4 + j) * 64 + l] =
                        g ? acc1[f][j] : acc0[f][j];
        }
        __syncthreads();
        if (wc == 0) {
#pragma unroll
            for (int f = 0; f < 16; ++f) {
                int h = f * 16 + lr;
#pragma unroll
                for (int j = 0; j < 4; ++j) {
                    int n = nrow + g * 16 + lg * 4 + j;
                    float v = (g ? acc1[f][j] : acc0[f][j]) +
                              lf[wr * 4096 + (f * 4 + j) * 64 + l];
                    pp[(long)n * EMB + h] = v;
                }
            }
        }
    }
}

// ---------------------------------------------------------------------------
// K3: out = relu(sum over 8 rg slices + F2f), vectorized f32x4
// ---------------------------------------------------------------------------
__global__ __launch_bounds__(256) void k3_reduce(
        const float* __restrict__ part, const float* __restrict__ F2f,
        float* __restrict__ out) {
    const long PS = (long)BS * NN * EMB;   // 1,048,576 floats per rg slice
    long i = ((long)blockIdx.x * 256 + threadIdx.x) * 4;
    f32x4 s = *(const f32x4*)(part + i);
#pragma unroll
    for (int rg = 1; rg < 8; ++rg)
        s += *(const f32x4*)(part + i + (long)rg * PS);
    s += *(const f32x4*)(F2f + i);
    f32x4 r;
#pragma unroll
    for (int j = 0; j < 4; ++j) r[j] = s[j] > 0.f ? s[j] : 0.f;
    *(f32x4*)(out + i) = r;
}

// ---------------------------------------------------------------------------
extern "C" void kernel_launch(void* const* d_in, const int* in_sizes, int n_in,
                              void* d_out, int out_size, void* d_ws, size_t ws_size,
                              hipStream_t stream) {
    const float* F   = (const float*)d_in[0];   // [8][512][256]
    const float* adj = (const float*)d_in[1];   // [8][16][512][512]
    const float* Wr  = (const float*)d_in[2];   // [16][256][256]
    const float* W0  = (const float*)d_in[3];   // [256][256]
    float* out = (float*)d_out;                 // [8][512][256]

    unsigned short* wT  = (unsigned short*)d_ws;             // 17*256*256 bf16
    unsigned short* Fbf = wT + 17 * 256 * 256;               // 8*512*256 bf16
    unsigned short* FW  = Fbf + (long)8 * 512 * 256;         // 8*16*64*2048 bf16
    float* F2f  = (float*)(FW + (long)8 * 16 * 64 * 2048);   // 8*512*256 f32
    float* part = F2f + (long)8 * 512 * 256;                 // 8*8*512*256 f32

    k0_prep<<<1600, 256, 0, stream>>>(Wr, W0, F, wT, Fbf);
    k1_fw<<<1088, 256, 0, stream>>>(Fbf, wT, FW, F2f);
    k2_main<<<256, 512, 0, stream>>>(adj, FW, part);
    k3_reduce<<<1024, 256, 0, stream>>>(part, F2f, out);
}